// Round 1
// baseline (140.518 us; speedup 1.0000x reference)
//
#include <hip/hip_runtime.h>

// LyapunovSDELayer: out[i, t] = f^t(lam0[i]), f(x) = clip(x + 0.5*(0.3 - x), 0, 1)
// With lam0 in [0,1), the clip is never active (values stay in [0.15, 0.65]
// after step 1; t=0 is the unclipped input itself), so the recurrence is
// affine: lam_t = 0.3 + 2^-t * (lam0 - 0.3). 2^-t scaling is exact via
// ldexpf; deviation from the iterated fp32 scan is contraction-damped
// (< ~1e-7, threshold 2e-2). Pure write-BW kernel: 134 MB out.

__global__ __launch_bounds__(256) void lyap_vec4_kernel(
    const float* __restrict__ lam0, float* __restrict__ out,
    int n_rows, int H, int quads_per_row) {
    int q = blockIdx.x * blockDim.x + threadIdx.x;
    int total = n_rows * quads_per_row;
    if (q >= total) return;
    int row = q / quads_per_row;            // one row per wave for H=256
    int t0  = (q - row * quads_per_row) * 4;

    float lam = lam0[row];                  // wave-uniform -> scalar load
    float d   = lam - 0.3f;
    float dd  = ldexpf(d, -t0);             // exact 2^-t0 scaling (underflows to 0 -> 0.3)

    float4 v;
    v.x = 0.3f + dd;
    v.y = fmaf(dd, 0.5f,   0.3f);
    v.z = fmaf(dd, 0.25f,  0.3f);
    v.w = fmaf(dd, 0.125f, 0.3f);
    if (t0 == 0) v.x = lam;                 // column 0 is the unmodified input

    *(float4*)(out + (size_t)row * H + t0) = v;   // 16B coalesced store
}

// Fallback for H not divisible by 4 (not hit for this problem's H=256).
__global__ __launch_bounds__(256) void lyap_scalar_kernel(
    const float* __restrict__ lam0, float* __restrict__ out,
    int n_rows, int H) {
    long long g = (long long)blockIdx.x * blockDim.x + threadIdx.x;
    long long total = (long long)n_rows * H;
    if (g >= total) return;
    int row = (int)(g / H);
    int t   = (int)(g - (long long)row * H);
    float lam = lam0[row];
    float v = (t == 0) ? lam : (0.3f + ldexpf(lam - 0.3f, -t));
    out[g] = v;
}

extern "C" void kernel_launch(void* const* d_in, const int* in_sizes, int n_in,
                              void* d_out, int out_size, void* d_ws, size_t ws_size,
                              hipStream_t stream) {
    const float* lam0 = (const float*)d_in[0];
    float* out = (float*)d_out;
    int n_rows = in_sizes[0];               // 131072
    int H = out_size / n_rows;              // 256

    if (H % 4 == 0) {
        int quads_per_row = H / 4;
        long long total = (long long)n_rows * quads_per_row;   // 8.4M threads
        int block = 256;
        int grid = (int)((total + block - 1) / block);
        lyap_vec4_kernel<<<grid, block, 0, stream>>>(lam0, out, n_rows, H, quads_per_row);
    } else {
        long long total = (long long)n_rows * H;
        int block = 256;
        int grid = (int)((total + block - 1) / block);
        lyap_scalar_kernel<<<grid, block, 0, stream>>>(lam0, out, n_rows, H);
    }
}

// Round 2
// 134.571 us; speedup vs baseline: 1.0442x; 1.0442x over previous
//
#include <hip/hip_runtime.h>

// LyapunovSDELayer: out[i, t] = f^t(lam0[i]), f(x) = clip(x + 0.5*(0.3 - x), 0, 1)
// lam0 in [0,1) => clip never fires; affine closed form:
//   lam_t = 0.3 + 2^-t * (lam0 - 0.3)   (exact 2^-t via ldexpf; deviation from
// the iterated fp32 scan is contraction-damped, << 2e-2 threshold).
// Pure write-BW kernel: 134 MB out. Write ceiling measured on this chip:
// ~6.6 TB/s (harness fill dispatches) => ~20 us floor + launch overhead.
//
// Layout (H == 256 fast path): one wave handles 4 rows. Lane l covers
// t0 = 4*l; each of the 4 stores is 64 lanes x 16 B = 1 KB contiguous
// (full cachelines, fully coalesced). 32768 waves total, shifts only —
// no integer division in the hot path.

__global__ __launch_bounds__(256) void lyap_h256_kernel(
    const float* __restrict__ lam0, float* __restrict__ out, int n_rows) {
    int g    = blockIdx.x * 256 + threadIdx.x;
    int lane = threadIdx.x & 63;
    int wave = g >> 6;                 // global wave id
    int row0 = wave << 2;              // 4 rows per wave
    if (row0 >= n_rows) return;
    int t0   = lane << 2;              // 0,4,...,252

    float4* dst = (float4*)(out + ((size_t)row0 << 8)) + lane;   // row0*256 + t0

#pragma unroll
    for (int r = 0; r < 4; ++r) {
        float lam = lam0[row0 + r];    // wave-uniform -> scalar load
        float dd  = ldexpf(lam - 0.3f, -t0);
        float4 v;
        v.x = 0.3f + dd;
        v.y = fmaf(dd, 0.5f,   0.3f);
        v.z = fmaf(dd, 0.25f,  0.3f);
        v.w = fmaf(dd, 0.125f, 0.3f);
        if (t0 == 0) v.x = lam;        // column 0 is the raw input
        dst[(size_t)r << 6] = v;       // += 256 floats per row
    }
}

// Generic fallback (any H) — not hit for this problem's H=256.
__global__ __launch_bounds__(256) void lyap_scalar_kernel(
    const float* __restrict__ lam0, float* __restrict__ out,
    int n_rows, int H) {
    long long g = (long long)blockIdx.x * blockDim.x + threadIdx.x;
    long long total = (long long)n_rows * H;
    if (g >= total) return;
    int row = (int)(g / H);
    int t   = (int)(g - (long long)row * H);
    float lam = lam0[row];
    out[g] = (t == 0) ? lam : (0.3f + ldexpf(lam - 0.3f, -t));
}

extern "C" void kernel_launch(void* const* d_in, const int* in_sizes, int n_in,
                              void* d_out, int out_size, void* d_ws, size_t ws_size,
                              hipStream_t stream) {
    const float* lam0 = (const float*)d_in[0];
    float* out = (float*)d_out;
    int n_rows = in_sizes[0];               // 131072
    int H = out_size / n_rows;              // 256

    if (H == 256 && (n_rows & 3) == 0) {
        int waves = n_rows >> 2;            // 4 rows per wave
        int threads = waves * 64;           // 2.10M
        int block = 256;
        int grid = (threads + block - 1) / block;   // 8192 blocks
        lyap_h256_kernel<<<grid, block, 0, stream>>>(lam0, out, n_rows);
    } else {
        long long total = (long long)n_rows * H;
        int block = 256;
        int grid = (int)((total + block - 1) / block);
        lyap_scalar_kernel<<<grid, block, 0, stream>>>(lam0, out, n_rows, H);
    }
}